// Round 1
// baseline (901.496 us; speedup 1.0000x reference)
//
#include <hip/hip_runtime.h>
#include <math.h>

#define B_ 64
#define N_ 16384
#define M_ 128
#define C_ 1024
#define EPS_ 1e-16f

__device__ __forceinline__ float softplus_(float x) {
    return fmaxf(x, 0.f) + log1pf(expf(-fabsf(x)));
}

// ---------------------------------------------------------------------------
// Kernel A: parameter projections. One block per batch, 128 threads.
// k = tanh(ctrl @ key_w + key_b); beta/gate/gamma/shift via strided dot +
// block reduction. erase/add are unused by the outputs -> skipped.
// ---------------------------------------------------------------------------
__global__ void proj_kernel(const float* __restrict__ ctrl,
                            const float* __restrict__ key_w, const float* __restrict__ key_b,
                            const float* __restrict__ beta_w, const float* __restrict__ beta_b,
                            const float* __restrict__ gate_w, const float* __restrict__ gate_b,
                            const float* __restrict__ shift_w, const float* __restrict__ shift_b,
                            const float* __restrict__ gamma_w, const float* __restrict__ gamma_b,
                            float* __restrict__ k_out, float* __restrict__ kn_out,
                            float* __restrict__ beta_out, float* __restrict__ gate_out,
                            float* __restrict__ gamma_out, float* __restrict__ shift_out)
{
    const int b = blockIdx.x;
    const int t = threadIdx.x;            // 128 threads, one per m
    const float* c = ctrl + (size_t)b * C_;

    float acc = 0.f;
    for (int i = 0; i < C_; ++i) acc = fmaf(c[i], key_w[i * M_ + t], acc);
    float kv = tanhf(acc + key_b[t]);
    k_out[b * M_ + t] = kv;

    float p0 = 0, p1 = 0, p2 = 0, p3 = 0, p4 = 0, p5 = 0;
    for (int i = t; i < C_; i += 128) {
        float cv = c[i];
        p0 = fmaf(cv, beta_w[i],      p0);
        p1 = fmaf(cv, gate_w[i],      p1);
        p2 = fmaf(cv, gamma_w[i],     p2);
        p3 = fmaf(cv, shift_w[3*i+0], p3);
        p4 = fmaf(cv, shift_w[3*i+1], p4);
        p5 = fmaf(cv, shift_w[3*i+2], p5);
    }
    __shared__ float red[7][128];
    red[0][t] = p0; red[1][t] = p1; red[2][t] = p2;
    red[3][t] = p3; red[4][t] = p4; red[5][t] = p5;
    red[6][t] = kv * kv;
    __syncthreads();
    for (int s = 64; s > 0; s >>= 1) {
        if (t < s) {
            #pragma unroll
            for (int j = 0; j < 7; ++j) red[j][t] += red[j][t + s];
        }
        __syncthreads();
    }
    if (t == 0) {
        beta_out[b]  = softplus_(red[0][0] + beta_b[0]);
        gate_out[b]  = 1.f / (1.f + expf(-(red[1][0] + gate_b[0])));
        gamma_out[b] = 1.f + softplus_(red[2][0] + gamma_b[0]);
        float z0 = red[3][0] + shift_b[0];
        float z1 = red[4][0] + shift_b[1];
        float z2 = red[5][0] + shift_b[2];
        float mx = fmaxf(z0, fmaxf(z1, z2));
        float e0 = expf(z0 - mx), e1 = expf(z1 - mx), e2 = expf(z2 - mx);
        float inv = 1.f / (e0 + e1 + e2);
        shift_out[b*3+0] = e0 * inv;
        shift_out[b*3+1] = e1 * inv;
        shift_out[b*3+2] = e2 * inv;
        kn_out[b] = sqrtf(red[6][0]);
    }
}

// ---------------------------------------------------------------------------
// Kernel B: content addressing. Half-wave-per-row float4 layout:
// lanes 0-31 of each half read one 512B memory row as float4 (the full
// 64-lane wave covers 2 consecutive rows = 1KB contiguous per vmem op).
// Shuffle-reduce the dot and the row sum-of-squares across 32 lanes, then
// e = exp(beta * dot / (||k||*||row|| + eps)). No max-subtraction needed:
// |beta*sim| <= beta ~ O(10), safely inside expf range.
// ---------------------------------------------------------------------------
#define ROWS_PER_CHUNK 1024
__global__ void content_kernel(const float* __restrict__ mem,
                               const float* __restrict__ k,
                               const float* __restrict__ kn,
                               const float* __restrict__ beta,
                               float* __restrict__ e_out,
                               float* __restrict__ sumE)
{
    const int b     = blockIdx.y;
    const int chunk = blockIdx.x;
    const int t     = threadIdx.x;        // 256 threads = 4 waves
    const int wave  = t >> 6;
    const int lane  = t & 63;
    const int half  = lane >> 5;
    const int sub   = lane & 31;

    __shared__ float ks[M_];
    if (t < M_) ks[t] = k[b * M_ + t];
    __syncthreads();
    const float4 k4  = reinterpret_cast<const float4*>(ks)[sub];
    const float  knb = kn[b];
    const float  bet = beta[b];

    const float* memb = mem + (size_t)b * N_ * M_;
    const int rowbase = chunk * ROWS_PER_CHUNK + wave * 2 + half;

    float eacc = 0.f;
    #pragma unroll 4
    for (int i = 0; i < ROWS_PER_CHUNK / 8; ++i) {
        const int n = rowbase + i * 8;
        const float4 m4 = reinterpret_cast<const float4*>(memb + (size_t)n * M_)[sub];
        float d = m4.x*k4.x + m4.y*k4.y + m4.z*k4.z + m4.w*k4.w;
        float q = m4.x*m4.x + m4.y*m4.y + m4.z*m4.z + m4.w*m4.w;
        #pragma unroll
        for (int off = 1; off < 32; off <<= 1) {   // stays within 32-lane half
            d += __shfl_xor(d, off, 64);
            q += __shfl_xor(q, off, 64);
        }
        if (sub == 0) {
            float sim = d / (knb * sqrtf(q) + EPS_);
            float ev  = expf(bet * sim);
            e_out[(size_t)b * N_ + n] = ev;
            eacc += ev;
        }
    }
    __shared__ float red[256];
    red[t] = eacc;
    __syncthreads();
    for (int s = 128; s > 0; s >>= 1) {
        if (t < s) red[t] += red[t + s];
        __syncthreads();
    }
    if (t == 0) atomicAdd(&sumE[b], red[0]);
}

// ---------------------------------------------------------------------------
// Kernel C: gated interpolation + circular 3-tap shift + sharpen (pow).
// One thread per slot n; neighbors re-read through cache.
// ---------------------------------------------------------------------------
__global__ void shiftpow_kernel(const float* __restrict__ e,
                                const float* __restrict__ prev,
                                const float* __restrict__ sumE,
                                const float* __restrict__ gate,
                                const float* __restrict__ shift,
                                const float* __restrict__ gamma,
                                float* __restrict__ wp_out,
                                float* __restrict__ sumWp)
{
    const int b = blockIdx.y;
    const int n = blockIdx.x * 256 + threadIdx.x;
    const float invE = 1.f / sumE[b];          // jax softmax: no eps in denom
    const float g    = gate[b];
    const float s0   = shift[b*3+0], s1 = shift[b*3+1], s2 = shift[b*3+2];
    const float gam  = gamma[b];
    const float* eb = e    + (size_t)b * N_;
    const float* pb = prev + (size_t)b * N_;

    const int nm = (n == 0)      ? N_ - 1 : n - 1;
    const int np = (n == N_ - 1) ? 0      : n + 1;
    float wm = g * eb[nm] * invE + (1.f - g) * pb[nm];
    float wc = g * eb[n]  * invE + (1.f - g) * pb[n];
    float wq = g * eb[np] * invE + (1.f - g) * pb[np];
    float wsft = s0 * wm + s1 * wc + s2 * wq;   // roll(+1)*s0 + w*s1 + roll(-1)*s2
    float wp = powf(wsft, gam);
    wp_out[(size_t)b * N_ + n] = wp;

    __shared__ float red[256];
    red[threadIdx.x] = wp;
    __syncthreads();
    for (int s = 128; s > 0; s >>= 1) {
        if (threadIdx.x < s) red[threadIdx.x] += red[threadIdx.x + s];
        __syncthreads();
    }
    if (threadIdx.x == 0) atomicAdd(&sumWp[b], red[0]);
}

// ---------------------------------------------------------------------------
// Kernel D: normalize sharpened weights -> d_out (float4 vectorized).
// ---------------------------------------------------------------------------
__global__ void normalize_kernel(const float* __restrict__ wp,
                                 const float* __restrict__ sumWp,
                                 float* __restrict__ out_w)
{
    const int b = blockIdx.y;
    const int i = blockIdx.x * 256 + threadIdx.x;     // over N/4
    const float inv = 1.f / (sumWp[b] + EPS_);
    float4 v = reinterpret_cast<const float4*>(wp + (size_t)b * N_)[i];
    v.x *= inv; v.y *= inv; v.z *= inv; v.w *= inv;
    reinterpret_cast<float4*>(out_w + (size_t)b * N_)[i] = v;
}

// ---------------------------------------------------------------------------
// Kernel E: weighted read. Same half-wave float4 layout as kernel B;
// weights for the chunk staged in LDS; per-lane float4 accumulator,
// LDS reduce across the 8 row-groups, atomicAdd partial into read_vec.
// ---------------------------------------------------------------------------
__global__ void read_kernel(const float* __restrict__ mem,
                            const float* __restrict__ weights,
                            float* __restrict__ read_out)
{
    const int b     = blockIdx.y;
    const int chunk = blockIdx.x;
    const int t     = threadIdx.x;        // 256
    const int wave  = t >> 6;
    const int lane  = t & 63;
    const int half  = lane >> 5;
    const int sub   = lane & 31;

    __shared__ float wtile[ROWS_PER_CHUNK];
    for (int i = t; i < ROWS_PER_CHUNK; i += 256)
        wtile[i] = weights[(size_t)b * N_ + chunk * ROWS_PER_CHUNK + i];
    __syncthreads();

    const float* memb = mem + (size_t)b * N_ * M_;
    const int rowbase = chunk * ROWS_PER_CHUNK + wave * 2 + half;
    const int lbase   = wave * 2 + half;

    float4 acc = make_float4(0.f, 0.f, 0.f, 0.f);
    #pragma unroll 4
    for (int i = 0; i < ROWS_PER_CHUNK / 8; ++i) {
        const int n  = rowbase + i * 8;
        const float wn = wtile[lbase + i * 8];          // LDS broadcast
        const float4 m4 = reinterpret_cast<const float4*>(memb + (size_t)n * M_)[sub];
        acc.x = fmaf(wn, m4.x, acc.x);
        acc.y = fmaf(wn, m4.y, acc.y);
        acc.z = fmaf(wn, m4.z, acc.z);
        acc.w = fmaf(wn, m4.w, acc.w);
    }
    __shared__ float red[8][32][4];
    const int g = wave * 2 + half;
    red[g][sub][0] = acc.x; red[g][sub][1] = acc.y;
    red[g][sub][2] = acc.z; red[g][sub][3] = acc.w;
    __syncthreads();
    if (t < M_) {
        const int m = t, s2 = m >> 2, c = m & 3;
        float s = 0.f;
        #pragma unroll
        for (int gg = 0; gg < 8; ++gg) s += red[gg][s2][c];
        atomicAdd(&read_out[b * M_ + m], s);
    }
}

// ---------------------------------------------------------------------------
extern "C" void kernel_launch(void* const* d_in, const int* in_sizes, int n_in,
                              void* d_out, int out_size, void* d_ws, size_t ws_size,
                              hipStream_t stream) {
    const float* ctrl    = (const float*)d_in[0];
    const float* prev_w  = (const float*)d_in[1];
    const float* memory  = (const float*)d_in[2];
    const float* key_w   = (const float*)d_in[3];
    const float* key_b   = (const float*)d_in[4];
    const float* beta_w  = (const float*)d_in[5];
    const float* beta_b  = (const float*)d_in[6];
    const float* gate_w  = (const float*)d_in[7];
    const float* gate_b  = (const float*)d_in[8];
    const float* shift_w = (const float*)d_in[9];
    const float* shift_b = (const float*)d_in[10];
    const float* gamma_w = (const float*)d_in[11];
    const float* gamma_b = (const float*)d_in[12];
    // d_in[13..16] = erase_w/b, add_w/b — unused by outputs.

    float* out   = (float*)d_out;          // [0, B*N) weights, [B*N, +B*M) read_vec
    float* ws    = (float*)d_ws;
    float* e     = ws;                                   // B*N
    float* wp    = ws + (size_t)B_ * N_;                 // B*N
    float* kbuf  = ws + (size_t)2 * B_ * N_;             // B*M
    float* kn    = kbuf  + B_ * M_;                      // B
    float* beta  = kn    + B_;                           // B
    float* gate  = beta  + B_;                           // B
    float* gamma = gate  + B_;                           // B
    float* shift = gamma + B_;                           // 3*B
    float* sums  = shift + 3 * B_;                       // sumE[B], sumWp[B]
    float* sumE  = sums;
    float* sumWp = sums + B_;

    hipMemsetAsync(sums, 0, 2 * B_ * sizeof(float), stream);
    hipMemsetAsync(out + (size_t)B_ * N_, 0, B_ * M_ * sizeof(float), stream);

    proj_kernel<<<B_, 128, 0, stream>>>(ctrl, key_w, key_b, beta_w, beta_b,
                                        gate_w, gate_b, shift_w, shift_b,
                                        gamma_w, gamma_b,
                                        kbuf, kn, beta, gate, gamma, shift);

    content_kernel<<<dim3(N_ / ROWS_PER_CHUNK, B_), 256, 0, stream>>>(
        memory, kbuf, kn, beta, e, sumE);

    shiftpow_kernel<<<dim3(N_ / 256, B_), 256, 0, stream>>>(
        e, prev_w, sumE, gate, shift, gamma, wp, sumWp);

    normalize_kernel<<<dim3(N_ / 4 / 256, B_), 256, 0, stream>>>(wp, sumWp, out);

    read_kernel<<<dim3(N_ / ROWS_PER_CHUNK, B_), 256, 0, stream>>>(
        memory, out, out + (size_t)B_ * N_);
}